// Round 2
// baseline (237.490 us; speedup 1.0000x reference)
//
#include <hip/hip_runtime.h>
#include <math.h>

// CPHASE on qubits (0,1) of a 22-qubit state, batch B=4 (innermost axis).
// Flat amplitude index: (((q0*2+q1) * 2^20 + rest) * 4 + b)  -> q01 = top 2 bits.
// Only the q01==3 quarter gets phase exp(i*theta[b]); the rest is a copy.
//
// Round-2 change: REVERT to the round-0 structure (2^22 threads, one v4f per
// array per thread, contiguous; wave-uniform branch) and remove ALL
// nontemporal hints. Rationale:
//  - Round-1 (4-chunk MLP) regressed 223.5 -> 234.8 us: MLP was already 7x
//    over-provisioned (64 KB in-flight/CU vs ~9 KB needed), and the strided
//    4-stream layout only added TLB/page spread. Structure reverted.
//  - The 'nt' bit is the only delta vs a plain float4 copy (6.3 TB/s, m13).
//    NT loads skip Infinity-Cache hits on freshly-restored inputs (128 MiB,
//    half of L3); NT stores take a different path than the 6.8 TB/s fills.
//    Plain loads/stores let L2/L3 do their normal job on a streaming kernel.
//
// Phase factors per-thread via native __sincosf (v_sin_f32/v_cos_f32):
// theta ~ N(0,1), precision ~1e-6 vs 0.108 threshold; VALU ~5% busy so the
// redundant transcendentals are free.

typedef float v4f __attribute__((ext_vector_type(4)));

#define N_ELEMS (1u << 24)          // 2^22 amplitudes * 4 batch
#define N_VEC   (N_ELEMS / 4u)      // one v4f (all 4 batch lanes) per thread
#define PHASE_START (3u << 20)      // first v4f index with q01==3 (block-aligned)

__global__ __launch_bounds__(256)
void CPHASE_34583076667990_kernel(const v4f* __restrict__ re_in,
                                  const v4f* __restrict__ im_in,
                                  const float* __restrict__ theta,
                                  v4f* __restrict__ out_re,
                                  v4f* __restrict__ out_im) {
    unsigned t = blockIdx.x * blockDim.x + threadIdx.x;  // [0, N_VEC)
    v4f re = re_in[t];
    v4f im = im_in[t];
    if (t >= PHASE_START) {                 // wave-uniform (boundary block-aligned)
        v4f c, s;
        float sv, cv;
        __sincosf(theta[0], &sv, &cv); c.x = cv; s.x = sv;
        __sincosf(theta[1], &sv, &cv); c.y = cv; s.y = sv;
        __sincosf(theta[2], &sv, &cv); c.z = cv; s.z = sv;
        __sincosf(theta[3], &sv, &cv); c.w = cv; s.w = sv;
        v4f nre = re * c - im * s;
        v4f nim = re * s + im * c;
        re = nre;
        im = nim;
    }
    out_re[t] = re;
    out_im[t] = im;
}

extern "C" void kernel_launch(void* const* d_in, const int* in_sizes, int n_in,
                              void* d_out, int out_size, void* d_ws, size_t ws_size,
                              hipStream_t stream) {
    const float* re    = (const float*)d_in[0];
    const float* im    = (const float*)d_in[1];
    const float* theta = (const float*)d_in[2];
    float* out = (float*)d_out;

    dim3 block(256);
    dim3 grid(N_VEC / 256);  // 2^22 / 256 = 16384 blocks
    CPHASE_34583076667990_kernel<<<grid, block, 0, stream>>>(
        (const v4f*)re, (const v4f*)im, theta,
        (v4f*)out, (v4f*)(out + N_ELEMS));
}

// Round 3
// 224.487 us; speedup vs baseline: 1.0579x; 1.0579x over previous
//
#include <hip/hip_runtime.h>
#include <math.h>

// CPHASE on qubits (0,1) of a 22-qubit state, batch B=4 (innermost axis).
// Flat amplitude index: (((q0*2+q1) * 2^20 + rest) * 4 + b)  -> q01 = top 2 bits.
// Only the q01==3 quarter gets phase exp(i*theta[b]); the rest is a copy.
//
// Empirical 2x2 so far (dur_us): NT+one-shot = 223.5 (best), NT+4-way-strided
// = 234.8, plain+one-shot = 237.5. NT hints are worth ~14 us -> KEEP them.
//
// Round-3 change (single variable vs round-0): grid-stride loop, 2048 blocks
// (Guideline 11: memory-bound -> cap ~2048 blocks, loop the rest). Round-0
// launched 65536 one-shot waves, each moving only 2 KiB read + 2 KiB write
// before dying -- per-wave fixed costs (kernarg s_load ~300cy, setup/drain)
// paid 64 sequential generations per SIMD. The 6.8 TB/s fill kernels on the
// same capture are small looping grids at 9% occupancy -- occupancy is NOT
// the streaming limiter, wave amortization is the remaining delta.
// '#pragma unroll 1' keeps iterations sequential in time: per-moment page
// footprint identical to round-0 (round-1's regression came from 8
// simultaneous far-apart pages per thread).
//
// Phase factors per-thread via native __sincosf (v_sin_f32/v_cos_f32):
// theta ~ N(0,1), precision ~1e-6 vs 0.108 threshold; VALU ~5% busy so the
// redundant transcendentals are free. Branch is wave-uniform: the q01==3
// boundary (3<<20) is a multiple of the per-iteration grid span.

typedef float v4f __attribute__((ext_vector_type(4)));

#define N_ELEMS (1u << 24)          // 2^22 amplitudes * 4 batch
#define N_VEC   (N_ELEMS / 4u)      // one v4f (all 4 batch lanes) per unit
#define PHASE_START (3u << 20)      // first v4f index with q01==3
#define NBLOCKS 2048u
#define BLOCK   256u
#define SPAN    (NBLOCKS * BLOCK)   // 2^19 v4f per sweep; 8 sweeps total

__global__ __launch_bounds__(BLOCK)
void CPHASE_34583076667990_kernel(const v4f* __restrict__ re_in,
                                  const v4f* __restrict__ im_in,
                                  const float* __restrict__ theta,
                                  v4f* __restrict__ out_re,
                                  v4f* __restrict__ out_im) {
    const unsigned gid = blockIdx.x * BLOCK + threadIdx.x;   // [0, SPAN)

    // Phase factors once per thread; latency hides under the first loads.
    v4f c, s;
    {
        float sv, cv;
        __sincosf(theta[0], &sv, &cv); c.x = cv; s.x = sv;
        __sincosf(theta[1], &sv, &cv); c.y = cv; s.y = sv;
        __sincosf(theta[2], &sv, &cv); c.z = cv; s.z = sv;
        __sincosf(theta[3], &sv, &cv); c.w = cv; s.w = sv;
    }

    #pragma unroll 1
    for (unsigned t = gid; t < N_VEC; t += SPAN) {
        v4f re = __builtin_nontemporal_load(&re_in[t]);
        v4f im = __builtin_nontemporal_load(&im_in[t]);
        if (t >= PHASE_START) {     // wave-uniform: boundary is SPAN-aligned
            v4f nre = re * c - im * s;
            v4f nim = re * s + im * c;
            re = nre;
            im = nim;
        }
        __builtin_nontemporal_store(re, &out_re[t]);
        __builtin_nontemporal_store(im, &out_im[t]);
    }
}

extern "C" void kernel_launch(void* const* d_in, const int* in_sizes, int n_in,
                              void* d_out, int out_size, void* d_ws, size_t ws_size,
                              hipStream_t stream) {
    const float* re    = (const float*)d_in[0];
    const float* im    = (const float*)d_in[1];
    const float* theta = (const float*)d_in[2];
    float* out = (float*)d_out;

    dim3 block(BLOCK);
    dim3 grid(NBLOCKS);
    CPHASE_34583076667990_kernel<<<grid, block, 0, stream>>>(
        (const v4f*)re, (const v4f*)im, theta,
        (v4f*)out, (v4f*)(out + N_ELEMS));
}

// Round 4
// 224.416 us; speedup vs baseline: 1.0583x; 1.0003x over previous
//
#include <hip/hip_runtime.h>
#include <math.h>

// CPHASE on qubits (0,1) of a 22-qubit state, batch B=4 (innermost axis).
// Flat amplitude index: (((q0*2+q1) * 2^20 + rest) * 4 + b)  -> q01 = top 2 bits.
// Only the q01==3 quarter gets phase exp(i*theta[b]); the rest is a copy.
//
// Ledger (dur_us; window = ~160us untouchable poison fills + kernel):
//   R0 NT-ld/NT-st one-shot     223.5  (kernel ~65.5)
//   R1 NT/NT 4-way strided      234.8  (MLP over-provisioned; regression)
//   R2 plain/plain one-shot     237.5  (kernel ~79)
//   R3 NT/NT grid-stride 2048   224.5  (kernel ~63.7; keep structure)
// The ONLY variable with a real delta is the NT bit (14 us, R0 vs R2), but
// R2 flipped loads AND stores together.
//
// Round-4 change (single variable vs R3): NT LOADS + PLAIN STORES.
// Mechanism: the 6.8 TB/s fill dispatches on every capture use plain stores
// -- full-line L2 write-allocate (no RFO: fills fetch ~15 KB vs 512 MiB
// written) and the L2 write-back scheduler batches dirty evictions into
// row-local DRAM bursts. NT stores bypass that batching. NT loads keep the
// 134 MB read stream from thrashing L2 and evicting not-yet-batched dirty
// lines. Predicts mixed cell best of all four; consistent with R0 > R2.
//
// Phase factors per-thread via native __sincosf (v_sin_f32/v_cos_f32):
// theta ~ N(0,1), precision ~1e-6 vs 0.108 threshold; VALU ~5% busy so the
// redundant transcendentals are free. Branch is wave-uniform: the q01==3
// boundary (3<<20) is a multiple of the per-iteration grid span.

typedef float v4f __attribute__((ext_vector_type(4)));

#define N_ELEMS (1u << 24)          // 2^22 amplitudes * 4 batch
#define N_VEC   (N_ELEMS / 4u)      // one v4f (all 4 batch lanes) per unit
#define PHASE_START (3u << 20)      // first v4f index with q01==3
#define NBLOCKS 2048u
#define BLOCK   256u
#define SPAN    (NBLOCKS * BLOCK)   // 2^19 v4f per sweep; 8 sweeps total

__global__ __launch_bounds__(BLOCK)
void CPHASE_34583076667990_kernel(const v4f* __restrict__ re_in,
                                  const v4f* __restrict__ im_in,
                                  const float* __restrict__ theta,
                                  v4f* __restrict__ out_re,
                                  v4f* __restrict__ out_im) {
    const unsigned gid = blockIdx.x * BLOCK + threadIdx.x;   // [0, SPAN)

    // Phase factors once per thread; latency hides under the first loads.
    v4f c, s;
    {
        float sv, cv;
        __sincosf(theta[0], &sv, &cv); c.x = cv; s.x = sv;
        __sincosf(theta[1], &sv, &cv); c.y = cv; s.y = sv;
        __sincosf(theta[2], &sv, &cv); c.z = cv; s.z = sv;
        __sincosf(theta[3], &sv, &cv); c.w = cv; s.w = sv;
    }

    #pragma unroll 1
    for (unsigned t = gid; t < N_VEC; t += SPAN) {
        v4f re = __builtin_nontemporal_load(&re_in[t]);   // NT: stay out of L2
        v4f im = __builtin_nontemporal_load(&im_in[t]);
        if (t >= PHASE_START) {     // wave-uniform: boundary is SPAN-aligned
            v4f nre = re * c - im * s;
            v4f nim = re * s + im * c;
            re = nre;
            im = nim;
        }
        out_re[t] = re;             // PLAIN: L2 write-allocate + batched
        out_im[t] = im;             //        dirty-eviction bursts (fill path)
    }
}

extern "C" void kernel_launch(void* const* d_in, const int* in_sizes, int n_in,
                              void* d_out, int out_size, void* d_ws, size_t ws_size,
                              hipStream_t stream) {
    const float* re    = (const float*)d_in[0];
    const float* im    = (const float*)d_in[1];
    const float* theta = (const float*)d_in[2];
    float* out = (float*)d_out;

    dim3 block(BLOCK);
    dim3 grid(NBLOCKS);
    CPHASE_34583076667990_kernel<<<grid, block, 0, stream>>>(
        (const v4f*)re, (const v4f*)im, theta,
        (v4f*)out, (v4f*)(out + N_ELEMS));
}